// Round 2
// baseline (164.886 us; speedup 1.0000x reference)
//
#include <hip/hip_runtime.h>
#include <hip/hip_bf16.h>

typedef float    f4   __attribute__((ext_vector_type(4)));
typedef short    s8v  __attribute__((ext_vector_type(8)));
typedef __bf16   bf8v __attribute__((ext_vector_type(8)));
typedef unsigned int u32x2 __attribute__((ext_vector_type(2)));
typedef unsigned short u16;

#define NB 8
#define NN 256
#define ND 128

static __device__ __forceinline__ u16 f2bf(float f) {
    union { float f; unsigned u; } v; v.f = f;
    unsigned r = v.u + 0x7FFF + ((v.u >> 16) & 1);   // RNE (used for weights)
    return (u16)(r >> 16);
}

// pack two f32 -> two bf16 (round-half-up via +0x8000, then v_perm pack)
static __device__ __forceinline__ unsigned pack2bf(float a, float b) {
    unsigned ua = __builtin_bit_cast(unsigned, a) + 0x8000u;
    unsigned ub = __builtin_bit_cast(unsigned, b) + 0x8000u;
    return __builtin_amdgcn_perm(ub, ua, 0x07060302u);  // {ua[31:16], ub[31:16]<<16}
}

// ---------------- precompute: P = x@W1a + b1m, Qt[b][d][j] = (x@W1b)[d], pack W1c frags
__global__ __launch_bounds__(256) void prep_kernel(
    const float* __restrict__ x, const float* __restrict__ W1m,
    const float* __restrict__ b1m,
    float* __restrict__ P, float* __restrict__ Qt, u16* __restrict__ W1cp)
{
    if (blockIdx.x == 1024) {
        // pack W1c (rows 256..383 of W1m) into MFMA B-fragment order:
        // frag[(kt*8+nt)*64 + lane][t] = W1c[kt*32 + (lane>>4)*8 + t][nt*16 + (lane&15)]
        for (int idx = threadIdx.x; idx < 16384; idx += 256) {
            int e  = idx & 7;
            int ln = (idx >> 3) & 63;
            int nt = (idx >> 9) & 7;
            int kt = idx >> 12;
            int k  = kt * 32 + (ln >> 4) * 8 + e;
            int d  = nt * 16 + (ln & 15);
            W1cp[idx] = f2bf(W1m[(2 * ND + k) * ND + d]);
        }
        return;
    }
    __shared__ float xl[256];
    int t = threadIdx.x;
    int row0 = blockIdx.x * 2;
    xl[t] = x[row0 * ND + t];
    __syncthreads();
    int r = t >> 7;            // 0..1
    int d = t & 127;
    int row = row0 + r;
    float sp = b1m[d], sq = 0.f;
    const float* xr = &xl[r * ND];
    #pragma unroll 8
    for (int k = 0; k < ND; ++k) {
        float xv = xr[k];
        sp += xv * W1m[k * ND + d];
        sq += xv * W1m[(ND + k) * ND + d];
    }
    P[row * ND + d] = sp;
    Qt[((size_t)((row >> 8) * ND + d)) * NN + (row & 255)] = sq;
}

// ---------------- fused: per-block (b,i): h=relu(E0@W1c + P_i + Q_j), masked sum,
//                  then node MLP (W2m fold, update MLP, residual, LayerNorm)
__global__ __launch_bounds__(256, 4) void fused_kernel(
    const float* __restrict__ x, const float* __restrict__ edge0,
    const int* __restrict__ mask,
    const float* __restrict__ W2m, const float* __restrict__ b2m,
    const float* __restrict__ W1u, const float* __restrict__ b1u,
    const float* __restrict__ W2u, const float* __restrict__ b2u,
    const float* __restrict__ gamma, const float* __restrict__ beta,
    const float* __restrict__ P, const float* __restrict__ Qt,
    const u16* __restrict__ W1cp,
    float* __restrict__ out)
{
    __shared__ u16   elds[64 * 128];   // 16 KB bf16 chunk, XOR-swizzled
    __shared__ float ml[NN];           // mask during main loop; partials in tail
    __shared__ float aggH[ND];
    __shared__ float xrow[ND];
    __shared__ float am[ND];
    __shared__ float hu[ND];
    __shared__ float yl[ND];
    __shared__ float redc[4], redA[4], redB[4];

    const int bid  = blockIdx.x;          // = b*256 + i
    const int b    = bid >> 8;
    const int tid  = threadIdx.x;
    const int wave = tid >> 6;
    const int lane = tid & 63;
    const int l15  = lane & 15;
    const int lg   = lane >> 4;

    const float* e0 = edge0 + (size_t)bid * (NN * ND);
    const f4* src = reinterpret_cast<const f4*>(e0);

    float mval = (float)mask[bid * NN + tid];
    ml[tid] = mval;
    if (tid < ND) xrow[tid] = x[bid * ND + tid];

    // B fragments for this wave's 32 output cols (nt = wave*2, wave*2+1)
    s8v bfr[4][2];
    #pragma unroll
    for (int kt = 0; kt < 4; ++kt)
        #pragma unroll
        for (int n = 0; n < 2; ++n)
            bfr[kt][n] = *reinterpret_cast<const s8v*>(
                &W1cp[(((kt * 8) + (wave * 2 + n)) * 64 + lane) * 8]);

    const int col0 = wave * 32 + l15;
    const float pv0 = P[bid * ND + col0];
    const float pv1 = P[bid * ND + col0 + 16];
    const float* qt0 = Qt + (size_t)(b * ND + col0) * NN;
    const float* qt1 = qt0 + (size_t)16 * NN;

    float agg0 = 0.f, agg1 = 0.f;

    // prologue: prefetch chunk 0 into registers
    f4 pre[8];
    #pragma unroll
    for (int u = 0; u < 8; ++u) pre[u] = src[u * 256 + tid];

    #pragma unroll
    for (int c = 0; c < 4; ++c) {
        // sync1: all waves done reading elds (chunk c-1); drains vmcnt -> pre ready
        __syncthreads();
        // ---- convert+write chunk c: regs -> bf16 LDS (swizzled) ----
        #pragma unroll
        for (int u = 0; u < 8; ++u) {
            int fi = u * 256 + tid;        // float4 index
            f4 v = pre[u];
            unsigned lo = pack2bf(v[0], v[1]);
            unsigned hi = pack2bf(v[2], v[3]);
            int row = fi >> 5;             // 32 float4 per row
            int c4  = fi & 31;
            int byteoff = (row << 8) + (((c4 << 3)) ^ ((row & 7) << 4));
            u32x2 pk; pk[0] = lo; pk[1] = hi;
            *reinterpret_cast<u32x2*>(reinterpret_cast<char*>(elds) + byteoff) = pk;
        }
        // ---- issue Q loads for chunk c (BEFORE edge prefetch: older in vmcnt queue) ----
        f4 qr0[4], qr1[4];
        #pragma unroll
        for (int m = 0; m < 4; ++m) {
            int j0 = c * 64 + m * 16 + lg * 4;
            qr0[m] = *reinterpret_cast<const f4*>(qt0 + j0);
            qr1[m] = *reinterpret_cast<const f4*>(qt1 + j0);
        }
        __builtin_amdgcn_sched_barrier(0);   // pin: Q issues before edge prefetch
        // ---- issue edge prefetch for chunk c+1 (stays in flight across barrier) ----
        if (c < 3) {
            #pragma unroll
            for (int u = 0; u < 8; ++u)
                pre[u] = src[(c + 1) * 2048 + u * 256 + tid];
        }
        // sync2: raw barrier — must NOT drain vmcnt (prefetch + Q in flight)
        asm volatile("s_waitcnt lgkmcnt(0)" ::: "memory");
        __builtin_amdgcn_s_barrier();
        __builtin_amdgcn_sched_barrier(0);
        // ---- compute: 64x128 @ 128x128 for this wave's 32 cols ----
        #pragma unroll
        for (int m = 0; m < 4; ++m) {
            f4 acc0 = {0.f, 0.f, 0.f, 0.f};
            f4 acc1 = {0.f, 0.f, 0.f, 0.f};
            int jl  = m * 16 + l15;
            int swz = (jl & 7) << 4;
            #pragma unroll
            for (int kt = 0; kt < 4; ++kt) {
                int byteoff = (jl << 8) + ((kt * 64 + lg * 16) ^ swz);
                s8v a = *reinterpret_cast<const s8v*>(
                    reinterpret_cast<const char*>(elds) + byteoff);
                acc0 = __builtin_amdgcn_mfma_f32_16x16x32_bf16(
                    __builtin_bit_cast(bf8v, a), __builtin_bit_cast(bf8v, bfr[kt][0]), acc0, 0, 0, 0);
                acc1 = __builtin_amdgcn_mfma_f32_16x16x32_bf16(
                    __builtin_bit_cast(bf8v, a), __builtin_bit_cast(bf8v, bfr[kt][1]), acc1, 0, 0, 0);
            }
            // rows j = c*64 + m*16 + lg*4 + r ; cols col0 / col0+16
            int j0 = c * 64 + m * 16 + lg * 4;
            f4 q0 = qr0[m];
            f4 q1 = qr1[m];
            #pragma unroll
            for (int r = 0; r < 4; ++r) {
                float mm = ml[j0 + r];
                float h0 = fmaxf(acc0[r] + pv0 + q0[r], 0.f);
                float h1 = fmaxf(acc1[r] + pv1 + q1[r], 0.f);
                agg0 += mm * h0;
                agg1 += mm * h1;
            }
        }
    }

    // reduce aggH partials across the 4 row-groups (lanes l, l+16, l+32, l+48)
    agg0 += __shfl_xor(agg0, 16); agg0 += __shfl_xor(agg0, 32);
    agg1 += __shfl_xor(agg1, 16); agg1 += __shfl_xor(agg1, 32);
    if (lg == 0) {
        aggH[wave * 32 + l15]      = agg0;
        aggH[wave * 32 + 16 + l15] = agg1;
    }
    // cnt = sum(mask)
    float cv = mval;
    #pragma unroll
    for (int o = 32; o > 0; o >>= 1) cv += __shfl_xor(cv, o);
    if (lane == 0) redc[wave] = cv;
    __syncthreads();

    const float cnt = redc[0] + redc[1] + redc[2] + redc[3];
    const float inv = 1.f / (cnt + 1e-6f);
    const int d  = tid & 127;
    const int hf = tid >> 7;

    // agg_msg = (aggH @ W2m + cnt*b2m) / (cnt+eps)   [K split across 2 thread halves]
    {
        float s = 0.f;
        #pragma unroll 8
        for (int k = hf * 64; k < hf * 64 + 64; ++k) s += aggH[k] * W2m[k * ND + d];
        ml[tid] = s;
    }
    __syncthreads();
    if (tid < ND) am[d] = (ml[d] + ml[d + ND] + cnt * b2m[d]) * inv;
    __syncthreads();
    // hu = relu([x, agg] @ W1u + b1u)   [half 0: x part, half 1: agg part]
    {
        float s = 0.f;
        const float* W = W1u + (size_t)hf * ND * ND;
        const float* v = hf ? am : xrow;
        #pragma unroll 8
        for (int k = 0; k < ND; ++k) s += v[k] * W[k * ND + d];
        ml[tid] = s;
    }
    __syncthreads();
    if (tid < ND) hu[d] = fmaxf(ml[d] + ml[d + ND] + b1u[d], 0.f);
    __syncthreads();
    // y = x + hu @ W2u + b2u   [K split across 2 thread halves]
    {
        float s = 0.f;
        #pragma unroll 8
        for (int k = hf * 64; k < hf * 64 + 64; ++k) s += hu[k] * W2u[k * ND + d];
        ml[tid] = s;
    }
    __syncthreads();
    if (tid < ND) yl[d] = xrow[d] + ml[d] + ml[d + ND] + b2u[d];
    __syncthreads();
    // LayerNorm over the 128 dims
    float yv = (tid < ND) ? yl[tid] : 0.f;
    float s1 = yv, s2 = yv * yv;
    #pragma unroll
    for (int o = 32; o > 0; o >>= 1) { s1 += __shfl_xor(s1, o); s2 += __shfl_xor(s2, o); }
    if (lane == 0) { redA[wave] = s1; redB[wave] = s2; }
    __syncthreads();
    if (tid < ND) {
        float mu  = (redA[0] + redA[1] + redA[2] + redA[3]) * (1.f / 128.f);
        float ex2 = (redB[0] + redB[1] + redB[2] + redB[3]) * (1.f / 128.f);
        float var = ex2 - mu * mu;
        float rs  = rsqrtf(var + 1e-5f);
        out[bid * ND + d] = (yl[d] - mu) * rs * gamma[d] + beta[d];
    }
}

extern "C" void kernel_launch(void* const* d_in, const int* in_sizes, int n_in,
                              void* d_out, int out_size, void* d_ws, size_t ws_size,
                              hipStream_t stream) {
    (void)in_sizes; (void)n_in; (void)out_size; (void)ws_size;
    const float* x     = (const float*)d_in[0];
    const float* edge0 = (const float*)d_in[1];
    const int*   mask  = (const int*)d_in[2];
    const float* W1m   = (const float*)d_in[3];
    const float* b1m   = (const float*)d_in[4];
    const float* W2m   = (const float*)d_in[5];
    const float* b2m   = (const float*)d_in[6];
    const float* W1u   = (const float*)d_in[7];
    const float* b1u   = (const float*)d_in[8];
    const float* W2u   = (const float*)d_in[9];
    const float* b2u   = (const float*)d_in[10];
    const float* gamma = (const float*)d_in[11];
    const float* beta  = (const float*)d_in[12];

    float* P    = (float*)d_ws;                 // 2048*128 f32 = 1 MB
    float* Qt   = P + 2048 * 128;               // 8*128*256 f32 = 1 MB
    u16*   W1cp = (u16*)(Qt + 8 * 128 * 256);   // 16384 bf16 = 32 KB

    float* o = (float*)d_out;

    prep_kernel<<<dim3(1025), dim3(256), 0, stream>>>(x, W1m, b1m, P, Qt, W1cp);
    fused_kernel<<<dim3(2048), dim3(256), 0, stream>>>(
        x, edge0, mask, W2m, b2m, W1u, b1u, W2u, b2u, gamma, beta,
        P, Qt, W1cp, o);
}

// Round 3
// 101.025 us; speedup vs baseline: 1.6321x; 1.6321x over previous
//
#include <hip/hip_runtime.h>
#include <hip/hip_bf16.h>

typedef float    f4    __attribute__((ext_vector_type(4)));
typedef short    s8v   __attribute__((ext_vector_type(8)));
typedef __bf16   bf8v  __attribute__((ext_vector_type(8)));
typedef unsigned int u32x4v __attribute__((ext_vector_type(4)));
typedef unsigned short u16;

typedef const __attribute__((address_space(1))) void GAS;
typedef __attribute__((address_space(3))) void LAS;

#define NB 8
#define NN 256
#define ND 128

static __device__ __forceinline__ u16 f2bf(float f) {
    union { float f; unsigned u; } v; v.f = f;
    unsigned r = v.u + 0x7FFF + ((v.u >> 16) & 1);   // RNE (weights)
    return (u16)(r >> 16);
}

// pack two f32 -> two bf16 (round-half-up via +0x8000, then v_perm pack)
static __device__ __forceinline__ unsigned pack2bf(float a, float b) {
    unsigned ua = __builtin_bit_cast(unsigned, a) + 0x8000u;
    unsigned ub = __builtin_bit_cast(unsigned, b) + 0x8000u;
    return __builtin_amdgcn_perm(ub, ua, 0x07060302u);  // {ua[31:16], ub[31:16]<<16}
}

// ---------------- precompute: P = x@W1a + b1m, Qt[b][d][j] = (x@W1b)[d], pack W1c frags
__global__ __launch_bounds__(256) void prep_kernel(
    const float* __restrict__ x, const float* __restrict__ W1m,
    const float* __restrict__ b1m,
    float* __restrict__ P, float* __restrict__ Qt, u16* __restrict__ W1cp)
{
    if (blockIdx.x == 1024) {
        // pack W1c (rows 256..383 of W1m) into MFMA B-fragment order:
        // frag[(kt*8+nt)*64 + lane][t] = W1c[kt*32 + (lane>>4)*8 + t][nt*16 + (lane&15)]
        for (int idx = threadIdx.x; idx < 16384; idx += 256) {
            int e  = idx & 7;
            int ln = (idx >> 3) & 63;
            int nt = (idx >> 9) & 7;
            int kt = idx >> 12;
            int k  = kt * 32 + (ln >> 4) * 8 + e;
            int d  = nt * 16 + (ln & 15);
            W1cp[idx] = f2bf(W1m[(2 * ND + k) * ND + d]);
        }
        return;
    }
    __shared__ float xl[256];
    int t = threadIdx.x;
    int row0 = blockIdx.x * 2;
    xl[t] = x[row0 * ND + t];
    __syncthreads();
    int r = t >> 7;            // 0..1
    int d = t & 127;
    int row = row0 + r;
    float sp = b1m[d], sq = 0.f;
    const float* xr = &xl[r * ND];
    #pragma unroll 8
    for (int k = 0; k < ND; ++k) {
        float xv = xr[k];
        sp += xv * W1m[k * ND + d];
        sq += xv * W1m[(ND + k) * ND + d];
    }
    P[row * ND + d] = sp;
    Qt[((size_t)((row >> 8) * ND + d)) * NN + (row & 255)] = sq;
}

// ---------------- fused: per-block (b,i): h=relu(E0@W1c + P_i + Q_j), masked sum,
//                  then node MLP (W2m fold, update MLP, residual, LayerNorm)
__global__ __launch_bounds__(256, 4) void fused_kernel(
    const float* __restrict__ x, const float* __restrict__ edge0,
    const int* __restrict__ mask,
    const float* __restrict__ W2m, const float* __restrict__ b2m,
    const float* __restrict__ W1u, const float* __restrict__ b1u,
    const float* __restrict__ W2u, const float* __restrict__ b2u,
    const float* __restrict__ gamma, const float* __restrict__ beta,
    const float* __restrict__ P, const float* __restrict__ Qt,
    const u16* __restrict__ W1cp,
    float* __restrict__ out)
{
    __shared__ float ebuf[2][32 * 128];   // 2 x 16KB raw f32 chunks (source-swizzled)
    __shared__ float ml[NN];              // mask during main loop; partials in tail
    __shared__ float aggH[ND];
    __shared__ float xrow[ND];
    __shared__ float am[ND];
    __shared__ float hu[ND];
    __shared__ float yl[ND];
    __shared__ float redc[4], redA[4], redB[4];

    const int bid  = blockIdx.x;          // = b*256 + i
    const int b    = bid >> 8;
    const int tid  = threadIdx.x;
    const int wave = tid >> 6;
    const int lane = tid & 63;
    const int l15  = lane & 15;
    const int lg   = lane >> 4;

    const char* e0c = (const char*)(edge0 + (size_t)bid * (NN * ND));

    float mval = (float)mask[bid * NN + tid];
    ml[tid] = mval;
    if (tid < ND) xrow[tid] = x[bid * ND + tid];

    // B fragments for this wave's 32 output cols (nt = wave*2, wave*2+1)
    s8v bfr[4][2];
    #pragma unroll
    for (int kt = 0; kt < 4; ++kt)
        #pragma unroll
        for (int n = 0; n < 2; ++n)
            bfr[kt][n] = *reinterpret_cast<const s8v*>(
                &W1cp[(((kt * 8) + (wave * 2 + n)) * 64 + lane) * 8]);

    const int col0 = wave * 32 + l15;
    const float pv0 = P[bid * ND + col0];
    const float pv1 = P[bid * ND + col0 + 16];
    const float* qt0 = Qt + (size_t)(b * ND + col0) * NN;
    const float* qt1 = qt0 + (size_t)16 * NN;

    // async stage chunk cc (32 rows x 128 f32 = 16KB) into buffer bb.
    // LDS dest is linear; source address carries the inverse XOR swizzle
    // (16B granular, ^(row&7)<<4) so swizzled reads see linear data.
    auto STAGE = [&](int cc, int bb) {
        const char* cb = e0c + (size_t)cc * 16384;
        #pragma unroll
        for (int u = 0; u < 4; ++u) {
            int row  = wave * 8 + u * 2 + (lane >> 5);
            int colb = (lane & 31) * 16;
            const char* g = cb + row * 512 + (colb ^ ((row & 7) << 4));
            __builtin_amdgcn_global_load_lds(
                (GAS*)g, (LAS*)&ebuf[bb][(wave * 4 + u) * 256], 16, 0, 0);
        }
    };

    float agg0 = 0.f, agg1 = 0.f;
    f4 q0r[2][2], q1r[2][2];

    // prologue: Q for chunk 0, then stage chunk 0
    #pragma unroll
    for (int m = 0; m < 2; ++m) {
        int j0 = m * 16 + lg * 4;
        q0r[0][m] = *reinterpret_cast<const f4*>(qt0 + j0);
        q1r[0][m] = *reinterpret_cast<const f4*>(qt1 + j0);
    }
    __builtin_amdgcn_sched_barrier(0);
    STAGE(0, 0);
    __builtin_amdgcn_sched_barrier(0);

    #pragma unroll
    for (int c = 0; c < 8; ++c) {
        const int pb = c & 1, nb = pb ^ 1;
        if (c < 7) {
            // issue Q for c+1 FIRST (older than stage in vmcnt queue)
            #pragma unroll
            for (int m = 0; m < 2; ++m) {
                int j0 = (c + 1) * 32 + m * 16 + lg * 4;
                q0r[nb][m] = *reinterpret_cast<const f4*>(qt0 + j0);
                q1r[nb][m] = *reinterpret_cast<const f4*>(qt1 + j0);
            }
            __builtin_amdgcn_sched_barrier(0);
            STAGE(c + 1, nb);
            __builtin_amdgcn_sched_barrier(0);
            // drain exactly stage_c (+older): 8 newest = Q_{c+1}(4) + stage_{c+1}(4)
            asm volatile("s_waitcnt vmcnt(8) lgkmcnt(0)" ::: "memory");
        } else {
            asm volatile("s_waitcnt vmcnt(0) lgkmcnt(0)" ::: "memory");
        }
        __builtin_amdgcn_s_barrier();
        __builtin_amdgcn_sched_barrier(0);

        const char* bufc = (const char*)&ebuf[pb][0];
        #pragma unroll
        for (int m = 0; m < 2; ++m) {
            f4 acc0 = {0.f, 0.f, 0.f, 0.f};
            f4 acc1 = {0.f, 0.f, 0.f, 0.f};
            int row = m * 16 + l15;
            int rb  = row * 512;
            int swz = (row & 7) << 4;
            #pragma unroll
            for (int kt = 0; kt < 4; ++kt) {
                int cbyte = kt * 128 + lg * 32;
                f4 a0 = *reinterpret_cast<const f4*>(bufc + rb + ((cbyte)      ^ swz));
                f4 a1 = *reinterpret_cast<const f4*>(bufc + rb + ((cbyte + 16) ^ swz));
                u32x4v aw;
                aw[0] = pack2bf(a0[0], a0[1]);
                aw[1] = pack2bf(a0[2], a0[3]);
                aw[2] = pack2bf(a1[0], a1[1]);
                aw[3] = pack2bf(a1[2], a1[3]);
                bf8v av = __builtin_bit_cast(bf8v, aw);
                acc0 = __builtin_amdgcn_mfma_f32_16x16x32_bf16(
                    av, __builtin_bit_cast(bf8v, bfr[kt][0]), acc0, 0, 0, 0);
                acc1 = __builtin_amdgcn_mfma_f32_16x16x32_bf16(
                    av, __builtin_bit_cast(bf8v, bfr[kt][1]), acc1, 0, 0, 0);
            }
            int j0 = c * 32 + m * 16 + lg * 4;
            f4 q0 = q0r[pb][m];
            f4 q1 = q1r[pb][m];
            #pragma unroll
            for (int r = 0; r < 4; ++r) {
                float mm = ml[j0 + r];
                float h0 = fmaxf(acc0[r] + pv0 + q0[r], 0.f);
                float h1 = fmaxf(acc1[r] + pv1 + q1[r], 0.f);
                agg0 += mm * h0;
                agg1 += mm * h1;
            }
        }
        __builtin_amdgcn_sched_barrier(0);
        __builtin_amdgcn_s_barrier();
    }

    // reduce agg partials across the 4 row-groups (lanes l, l+16, l+32, l+48)
    agg0 += __shfl_xor(agg0, 16); agg0 += __shfl_xor(agg0, 32);
    agg1 += __shfl_xor(agg1, 16); agg1 += __shfl_xor(agg1, 32);
    if (lg == 0) {
        aggH[wave * 32 + l15]      = agg0;
        aggH[wave * 32 + 16 + l15] = agg1;
    }
    // cnt = sum(mask)
    float cv = mval;
    #pragma unroll
    for (int o = 32; o > 0; o >>= 1) cv += __shfl_xor(cv, o);
    if (lane == 0) redc[wave] = cv;
    __syncthreads();

    const float cnt = redc[0] + redc[1] + redc[2] + redc[3];
    const float inv = 1.f / (cnt + 1e-6f);
    const int d  = tid & 127;
    const int hf = tid >> 7;

    // agg_msg = (aggH @ W2m + cnt*b2m) / (cnt+eps)   [K split across 2 thread halves]
    {
        float s = 0.f;
        #pragma unroll 8
        for (int k = hf * 64; k < hf * 64 + 64; ++k) s += aggH[k] * W2m[k * ND + d];
        ml[tid] = s;
    }
    __syncthreads();
    if (tid < ND) am[d] = (ml[d] + ml[d + ND] + cnt * b2m[d]) * inv;
    __syncthreads();
    // hu = relu([x, agg] @ W1u + b1u)   [half 0: x part, half 1: agg part]
    {
        float s = 0.f;
        const float* W = W1u + (size_t)hf * ND * ND;
        const float* v = hf ? am : xrow;
        #pragma unroll 8
        for (int k = 0; k < ND; ++k) s += v[k] * W[k * ND + d];
        ml[tid] = s;
    }
    __syncthreads();
    if (tid < ND) hu[d] = fmaxf(ml[d] + ml[d + ND] + b1u[d], 0.f);
    __syncthreads();
    // y = x + hu @ W2u + b2u   [K split across 2 thread halves]
    {
        float s = 0.f;
        #pragma unroll 8
        for (int k = hf * 64; k < hf * 64 + 64; ++k) s += hu[k] * W2u[k * ND + d];
        ml[tid] = s;
    }
    __syncthreads();
    if (tid < ND) yl[d] = xrow[d] + ml[d] + ml[d + ND] + b2u[d];
    __syncthreads();
    // LayerNorm over the 128 dims
    float yv = (tid < ND) ? yl[tid] : 0.f;
    float s1 = yv, s2 = yv * yv;
    #pragma unroll
    for (int o = 32; o > 0; o >>= 1) { s1 += __shfl_xor(s1, o); s2 += __shfl_xor(s2, o); }
    if (lane == 0) { redA[wave] = s1; redB[wave] = s2; }
    __syncthreads();
    if (tid < ND) {
        float mu  = (redA[0] + redA[1] + redA[2] + redA[3]) * (1.f / 128.f);
        float ex2 = (redB[0] + redB[1] + redB[2] + redB[3]) * (1.f / 128.f);
        float var = ex2 - mu * mu;
        float rs  = rsqrtf(var + 1e-5f);
        out[bid * ND + d] = (yl[d] - mu) * rs * gamma[d] + beta[d];
    }
}

extern "C" void kernel_launch(void* const* d_in, const int* in_sizes, int n_in,
                              void* d_out, int out_size, void* d_ws, size_t ws_size,
                              hipStream_t stream) {
    (void)in_sizes; (void)n_in; (void)out_size; (void)ws_size;
    const float* x     = (const float*)d_in[0];
    const float* edge0 = (const float*)d_in[1];
    const int*   mask  = (const int*)d_in[2];
    const float* W1m   = (const float*)d_in[3];
    const float* b1m   = (const float*)d_in[4];
    const float* W2m   = (const float*)d_in[5];
    const float* b2m   = (const float*)d_in[6];
    const float* W1u   = (const float*)d_in[7];
    const float* b1u   = (const float*)d_in[8];
    const float* W2u   = (const float*)d_in[9];
    const float* b2u   = (const float*)d_in[10];
    const float* gamma = (const float*)d_in[11];
    const float* beta  = (const float*)d_in[12];

    float* P    = (float*)d_ws;                 // 2048*128 f32 = 1 MB
    float* Qt   = P + 2048 * 128;               // 8*128*256 f32 = 1 MB
    u16*   W1cp = (u16*)(Qt + 8 * 128 * 256);   // 16384 bf16 = 32 KB

    float* o = (float*)d_out;

    prep_kernel<<<dim3(1025), dim3(256), 0, stream>>>(x, W1m, b1m, P, Qt, W1cp);
    fused_kernel<<<dim3(2048), dim3(256), 0, stream>>>(
        x, edge0, mask, W2m, b2m, W1u, b1u, W2u, b2u, gamma, beta,
        P, Qt, W1cp, o);
}